// Round 6
// baseline (553.487 us; speedup 1.0000x reference)
//
#include <hip/hip_runtime.h>
#include <math.h>

#define NB 8192
#define H 1024
#define HH 512
#define NEXP 16
#define NT64 144            // max sum of per-expert ceil(cnt/64)
#define AMBIG_THR 0.04f     // ~6.7 sigma of plain-bf16 logit error

// MFMA 16x16x32 bf16 fragments
typedef __attribute__((ext_vector_type(8))) short bfrag;
typedef __attribute__((ext_vector_type(4))) float f4;

__device__ __forceinline__ f4 MF(bfrag a, bfrag b, f4 c) {
    return __builtin_amdgcn_mfma_f32_16x16x32_bf16(a, b, c, 0, 0, 0);
}
__device__ __forceinline__ unsigned short f2bf(float f) {  // RNE fp32->bf16
    unsigned u = __float_as_uint(f);
    u += 0x7fff + ((u >> 16) & 1);
    return (unsigned short)(u >> 16);
}

// one fused plain conversion for everything; block 0 zeroes counters.
// blocks: q 8192 | w1 512 | w3 8 | ew1 8192 | ew2 8192  => 16904+8192=25096? no:
// q:8192, w1:512, w3:8, ew1:8192, ew2:8192 -> total 25096... (8192+512+8+8192+8192=25096)
__global__ __launch_bounds__(256) void cvt_kernel(
    const float* __restrict__ q, const float* __restrict__ w1, const float* __restrict__ w3,
    const float* __restrict__ ew1, const float* __restrict__ ew2,
    unsigned short* __restrict__ qb, unsigned short* __restrict__ w1b,
    unsigned short* __restrict__ w3b, unsigned short* __restrict__ ew1b,
    unsigned short* __restrict__ ew2b,
    int* __restrict__ counts, int* __restrict__ ambig_cnt)
{
    const int b = blockIdx.x, t = threadIdx.x;
    if (b == 0) {
        if (t < NEXP) counts[t] = 0;
        if (t == NEXP) ambig_cnt[0] = 0;
    }
    const float* src; unsigned short* dst; int i;
    if (b < 8192)       { src = q;   dst = qb;   i = b * 256 + t; }
    else if (b < 8704)  { src = w1;  dst = w1b;  i = (b - 8192) * 256 + t; }
    else if (b < 8712)  { src = w3;  dst = w3b;  i = (b - 8704) * 256 + t; }
    else if (b < 16904) { src = ew1; dst = ew1b; i = (b - 8712) * 256 + t; }
    else                { src = ew2; dst = ew2b; i = (b - 16904) * 256 + t; }
    float4 v = ((const float4*)src)[i];
    ushort4 h;
    h.x = f2bf(v.x); h.y = f2bf(v.y); h.z = f2bf(v.z); h.w = f2bf(v.w);
    ((ushort4*)dst)[i] = h;
}

// ---- gating GEMM1 (plain bf16): x1 = relu(q @ w1^T + b1) ----
// single-wave; wave tile 64 rows x 64 cols; grid (128, 8).
__global__ __launch_bounds__(64) void g1_kernel(
    const unsigned short* __restrict__ qb, const unsigned short* __restrict__ w1b,
    const float* __restrict__ b1, unsigned short* __restrict__ x1)
{
    const int lane = threadIdx.x & 63, quad = lane >> 4, l16 = lane & 15;
    const int row0 = blockIdx.x * 64;
    const int c0 = blockIdx.y * 64;
    const f4 z4 = {0.f, 0.f, 0.f, 0.f};
    f4 acc[4][4];
    #pragma unroll
    for (int rb = 0; rb < 4; ++rb)
        #pragma unroll
        for (int cb = 0; cb < 4; ++cb) acc[rb][cb] = z4;

    size_t ar[4], br[4];
    #pragma unroll
    for (int j = 0; j < 4; ++j) {
        ar[j] = (size_t)(row0 + j * 16 + l16) * H + quad * 8;
        br[j] = (size_t)(c0 + j * 16 + l16) * H + quad * 8;
    }
    bfrag a[4], b[4];
    #pragma unroll
    for (int j = 0; j < 4; ++j) {
        a[j] = *(const bfrag*)(qb + ar[j]);
        b[j] = *(const bfrag*)(w1b + br[j]);
    }
    #pragma unroll 2
    for (int kk = 32; kk < H; kk += 32) {
        bfrag na[4], nb[4];
        #pragma unroll
        for (int j = 0; j < 4; ++j) {
            na[j] = *(const bfrag*)(qb + ar[j] + kk);
            nb[j] = *(const bfrag*)(w1b + br[j] + kk);
        }
        #pragma unroll
        for (int rb = 0; rb < 4; ++rb)
            #pragma unroll
            for (int cb = 0; cb < 4; ++cb)
                acc[rb][cb] = MF(a[rb], b[cb], acc[rb][cb]);
        #pragma unroll
        for (int j = 0; j < 4; ++j) { a[j] = na[j]; b[j] = nb[j]; }
    }
    #pragma unroll
    for (int rb = 0; rb < 4; ++rb)
        #pragma unroll
        for (int cb = 0; cb < 4; ++cb)
            acc[rb][cb] = MF(a[rb], b[cb], acc[rb][cb]);

    #pragma unroll
    for (int cb = 0; cb < 4; ++cb) {
        int col = c0 + cb * 16 + l16;
        float bias = b1[col];
        #pragma unroll
        for (int rb = 0; rb < 4; ++rb)
            #pragma unroll
            for (int i = 0; i < 4; ++i) {
                int row = rb * 16 + quad * 4 + i;
                x1[(size_t)(row0 + row) * HH + col] = f2bf(fmaxf(acc[rb][cb][i] + bias, 0.f));
            }
    }
}

// ---- logits (plain) + argmax + gate + counts + ambiguity flag ----
__global__ __launch_bounds__(256) void logits_kernel(
    const unsigned short* __restrict__ x1, const unsigned short* __restrict__ w3b,
    const float* __restrict__ b3,
    int* __restrict__ top1, float* __restrict__ gval, int* __restrict__ counts,
    int* __restrict__ ambig_rows, int* __restrict__ ambig_cnt)
{
    __shared__ float lgp[4][32][NEXP];
    const int t = threadIdx.x, wave = t >> 6, lane = t & 63;
    const int quad = lane >> 4, l16 = lane & 15;
    const int row0 = blockIdx.x * 32;
    const f4 z4 = {0.f, 0.f, 0.f, 0.f};

    f4 l0 = z4, l1 = z4;
    const size_t ar0 = (size_t)(row0 + l16) * HH + quad * 8;
    const size_t ar1 = ar0 + (size_t)16 * HH;
    const size_t br = (size_t)l16 * HH + quad * 8;
    #pragma unroll
    for (int ks = 0; ks < 4; ++ks) {
        int kk = wave * 128 + ks * 32;
        bfrag a0 = *(const bfrag*)(x1 + ar0 + kk);
        bfrag a1 = *(const bfrag*)(x1 + ar1 + kk);
        bfrag b  = *(const bfrag*)(w3b + br + kk);
        l0 = MF(a0, b, l0);
        l1 = MF(a1, b, l1);
    }
    #pragma unroll
    for (int i = 0; i < 4; ++i) {
        lgp[wave][quad * 4 + i][l16] = l0[i];
        lgp[wave][16 + quad * 4 + i][l16] = l1[i];
    }
    __syncthreads();

    if (t < 32) {
        float lg[NEXP];
        #pragma unroll
        for (int m = 0; m < NEXP; ++m)
            lg[m] = lgp[0][t][m] + lgp[1][t][m] + lgp[2][t][m] + lgp[3][t][m] + b3[m];
        float best = lg[0], second = -3.4e38f; int bi = 0;
        #pragma unroll
        for (int m = 1; m < NEXP; ++m) {
            float v = lg[m];
            if (v > best) { second = best; best = v; bi = m; }
            else if (v > second) second = v;
        }
        float se = 0.f;
        #pragma unroll
        for (int m = 0; m < NEXP; ++m) se += expf(lg[m] - best);
        int grow = row0 + t;
        top1[grow] = bi;
        gval[grow] = 1.f / se;
        atomicAdd(&counts[bi], 1);
        if (best - second < AMBIG_THR) {
            int pos = atomicAdd(ambig_cnt, 1);
            if (pos < NB) ambig_rows[pos] = grow;
        }
    }
}

// ---- exact fp32 recompute for ambiguous rows (coalesced w1 reads) ----
__global__ __launch_bounds__(256) void fixup_kernel(
    const float* __restrict__ q, const float* __restrict__ w1, const float* __restrict__ b1,
    const float* __restrict__ w3, const float* __restrict__ b3,
    const int* __restrict__ ambig_rows, const int* __restrict__ ambig_cnt,
    int* __restrict__ top1, float* __restrict__ gval, int* __restrict__ counts)
{
    __shared__ __align__(16) float qrow[H];
    __shared__ __align__(16) float x1[HH];
    __shared__ float lgs[NEXP];
    const int t = threadIdx.x, wv = t >> 6, ln = t & 63;
    int nn = *ambig_cnt; if (nn > NB) nn = NB;
    for (int ii = blockIdx.x; ii < nn; ii += gridDim.x) {
        int row = ambig_rows[ii];
        ((float4*)qrow)[t] = ((const float4*)(q + (size_t)row * H))[t];
        __syncthreads();
        for (int c = wv * 2; c < HH; c += 8) {
            const float4* w0 = (const float4*)(w1 + (size_t)c * H);
            const float4* w1r = (const float4*)(w1 + (size_t)(c + 1) * H);
            const float4* qv = (const float4*)qrow;
            float s0 = 0.f, s1 = 0.f;
            #pragma unroll
            for (int j = 0; j < 4; ++j) {
                float4 a = qv[j * 64 + ln];
                float4 b0 = w0[j * 64 + ln];
                float4 b1v = w1r[j * 64 + ln];
                s0 += a.x * b0.x + a.y * b0.y + a.z * b0.z + a.w * b0.w;
                s1 += a.x * b1v.x + a.y * b1v.y + a.z * b1v.z + a.w * b1v.w;
            }
            #pragma unroll
            for (int off = 32; off; off >>= 1) {
                s0 += __shfl_xor(s0, off, 64);
                s1 += __shfl_xor(s1, off, 64);
            }
            if (ln == 0) {
                x1[c]     = fmaxf(s0 + b1[c], 0.f);
                x1[c + 1] = fmaxf(s1 + b1[c + 1], 0.f);
            }
        }
        __syncthreads();
        for (int m = wv; m < NEXP; m += 4) {
            const float4* wr = (const float4*)(w3 + (size_t)m * HH);
            const float4* xv = (const float4*)x1;
            float s = 0.f;
            #pragma unroll
            for (int j = 0; j < 2; ++j) {
                float4 a = xv[j * 64 + ln];
                float4 b = wr[j * 64 + ln];
                s += a.x * b.x + a.y * b.y + a.z * b.z + a.w * b.w;
            }
            #pragma unroll
            for (int off = 32; off; off >>= 1) s += __shfl_xor(s, off, 64);
            if (ln == 0) lgs[m] = s + b3[m];
        }
        __syncthreads();
        if (t == 0) {
            float best = lgs[0]; int bi = 0;
            #pragma unroll
            for (int m = 1; m < NEXP; ++m) if (lgs[m] > best) { best = lgs[m]; bi = m; }
            float se = 0.f;
            #pragma unroll
            for (int m = 0; m < NEXP; ++m) se += expf(lgs[m] - best);
            int old = top1[row];
            if (bi != old) {
                atomicSub(&counts[old], 1);
                atomicAdd(&counts[bi], 1);
                top1[row] = bi;
            }
            gval[row] = 1.f / se;
        }
        __syncthreads();
    }
}

// offsets + 64-row tile map
__global__ __launch_bounds__(64) void offsets_kernel(
    const int* __restrict__ counts, int* __restrict__ offsets, int* __restrict__ bpos,
    int* __restrict__ tm_e, int* __restrict__ tm_p, int* __restrict__ tm_end)
{
    if (threadIdx.x == 0) {
        int run = 0;
        for (int e = 0; e < NEXP; ++e) { offsets[e] = run; bpos[e] = run; run += counts[e]; }
        int tile = 0;
        for (int e = 0; e < NEXP; ++e) {
            int beg = offsets[e], end = beg + counts[e];
            for (int p = beg; p < end; p += 64) {
                tm_e[tile] = e; tm_p[tile] = p; tm_end[tile] = end; ++tile;
            }
        }
        for (; tile < NT64; ++tile) tm_e[tile] = -1;
    }
}

__global__ __launch_bounds__(256) void scatter_kernel(
    const int* __restrict__ top1, int* __restrict__ bpos, int* __restrict__ brows)
{
    int b = blockIdx.x * 256 + threadIdx.x;
    int e = top1[b];
    int pos = atomicAdd(&bpos[e], 1);
    brows[pos] = b;
}

// ---- expert GEMM1: h[pos][512] = relu(q[row] @ w1[e]^T + b1[e]) ----
// single-wave; wave tile 64 x 64; grid (NT64, 8).
__global__ __launch_bounds__(64) void exp1_kernel(
    const unsigned short* __restrict__ qb, const unsigned short* __restrict__ ew1b,
    const float* __restrict__ eb1,
    const int* __restrict__ tm_e, const int* __restrict__ tm_p, const int* __restrict__ tm_end,
    const int* __restrict__ brows, unsigned short* __restrict__ h)
{
    const int e = tm_e[blockIdx.x];
    if (e < 0) return;
    const int p0 = tm_p[blockIdx.x], end = tm_end[blockIdx.x];
    const int lane = threadIdx.x & 63, quad = lane >> 4, l16 = lane & 15;
    const int c0 = blockIdx.y * 64;
    const unsigned short* w1p = ew1b + (size_t)e * HH * H;
    const f4 z4 = {0.f, 0.f, 0.f, 0.f};
    f4 acc[4][4];
    #pragma unroll
    for (int rb = 0; rb < 4; ++rb)
        #pragma unroll
        for (int cb = 0; cb < 4; ++cb) acc[rb][cb] = z4;

    size_t ar[4], br[4];
    #pragma unroll
    for (int j = 0; j < 4; ++j) {
        int p = p0 + j * 16 + l16; if (p >= end) p = end - 1;
        ar[j] = (size_t)brows[p] * H + quad * 8;
        br[j] = (size_t)(c0 + j * 16 + l16) * H + quad * 8;
    }
    bfrag a[4], b[4];
    #pragma unroll
    for (int j = 0; j < 4; ++j) {
        a[j] = *(const bfrag*)(qb + ar[j]);
        b[j] = *(const bfrag*)(w1p + br[j]);
    }
    #pragma unroll 2
    for (int kk = 32; kk < H; kk += 32) {
        bfrag na[4], nb[4];
        #pragma unroll
        for (int j = 0; j < 4; ++j) {
            na[j] = *(const bfrag*)(qb + ar[j] + kk);
            nb[j] = *(const bfrag*)(w1p + br[j] + kk);
        }
        #pragma unroll
        for (int rb = 0; rb < 4; ++rb)
            #pragma unroll
            for (int cb = 0; cb < 4; ++cb)
                acc[rb][cb] = MF(a[rb], b[cb], acc[rb][cb]);
        #pragma unroll
        for (int j = 0; j < 4; ++j) { a[j] = na[j]; b[j] = nb[j]; }
    }
    #pragma unroll
    for (int rb = 0; rb < 4; ++rb)
        #pragma unroll
        for (int cb = 0; cb < 4; ++cb)
            acc[rb][cb] = MF(a[rb], b[cb], acc[rb][cb]);

    #pragma unroll
    for (int cb = 0; cb < 4; ++cb) {
        int col = c0 + cb * 16 + l16;
        float bias = eb1[e * HH + col];
        #pragma unroll
        for (int rb = 0; rb < 4; ++rb)
            #pragma unroll
            for (int i = 0; i < 4; ++i) {
                int row = rb * 16 + quad * 4 + i;
                if (p0 + row < end)
                    h[(size_t)(p0 + row) * HH + col] = f2bf(fmaxf(acc[rb][cb][i] + bias, 0.f));
            }
    }
}

// ---- expert GEMM2: v = h @ w2[e]^T + b2[e]; psum[row][cg] = partial sum v^2 ----
// single-wave; wave tile 64 x 64; grid (NT64, 16).
__global__ __launch_bounds__(64) void exp2_kernel(
    const unsigned short* __restrict__ h, const unsigned short* __restrict__ ew2b,
    const float* __restrict__ eb2,
    const int* __restrict__ tm_e, const int* __restrict__ tm_p, const int* __restrict__ tm_end,
    const int* __restrict__ brows,
    float* __restrict__ vout, float* __restrict__ psum)
{
    const int e = tm_e[blockIdx.x];
    if (e < 0) return;
    const int p0 = tm_p[blockIdx.x], end = tm_end[blockIdx.x];
    const int lane = threadIdx.x & 63, quad = lane >> 4, l16 = lane & 15;
    const int cg = blockIdx.y;
    const int c0 = cg * 64;
    const unsigned short* w2p = ew2b + (size_t)e * H * HH;
    const f4 z4 = {0.f, 0.f, 0.f, 0.f};
    f4 acc[4][4];
    #pragma unroll
    for (int rb = 0; rb < 4; ++rb)
        #pragma unroll
        for (int cb = 0; cb < 4; ++cb) acc[rb][cb] = z4;

    size_t ar[4], br[4];
    #pragma unroll
    for (int j = 0; j < 4; ++j) {
        int p = p0 + j * 16 + l16; if (p >= end) p = end - 1;
        ar[j] = (size_t)p * HH + quad * 8;
        br[j] = (size_t)(c0 + j * 16 + l16) * HH + quad * 8;
    }
    bfrag a[4], b[4];
    #pragma unroll
    for (int j = 0; j < 4; ++j) {
        a[j] = *(const bfrag*)(h + ar[j]);
        b[j] = *(const bfrag*)(w2p + br[j]);
    }
    #pragma unroll 2
    for (int kk = 32; kk < HH; kk += 32) {
        bfrag na[4], nb[4];
        #pragma unroll
        for (int j = 0; j < 4; ++j) {
            na[j] = *(const bfrag*)(h + ar[j] + kk);
            nb[j] = *(const bfrag*)(w2p + br[j] + kk);
        }
        #pragma unroll
        for (int rb = 0; rb < 4; ++rb)
            #pragma unroll
            for (int cb = 0; cb < 4; ++cb)
                acc[rb][cb] = MF(a[rb], b[cb], acc[rb][cb]);
        #pragma unroll
        for (int j = 0; j < 4; ++j) { a[j] = na[j]; b[j] = nb[j]; }
    }
    #pragma unroll
    for (int rb = 0; rb < 4; ++rb)
        #pragma unroll
        for (int cb = 0; cb < 4; ++cb)
            acc[rb][cb] = MF(a[rb], b[cb], acc[rb][cb]);

    // bias + v-write + per-row sum(v^2)
    float rs[4][4];
    #pragma unroll
    for (int rb = 0; rb < 4; ++rb) {
        #pragma unroll
        for (int i = 0; i < 4; ++i) {
            int row = rb * 16 + quad * 4 + i;
            int gp = p0 + row; if (gp >= end) gp = end - 1;
            int gr = brows[gp];
            float s = 0.f;
            #pragma unroll
            for (int cb = 0; cb < 4; ++cb) {
                int col = c0 + cb * 16 + l16;
                float v = acc[rb][cb][i] + eb2[e * H + col];
                vout[(size_t)gr * H + col] = v;
                s += v * v;
            }
            rs[rb][i] = s;
        }
    }
    #pragma unroll
    for (int rb = 0; rb < 4; ++rb)
        #pragma unroll
        for (int i = 0; i < 4; ++i) {
            float s = rs[rb][i];
            #pragma unroll
            for (int off = 8; off; off >>= 1) s += __shfl_xor(s, off, 16);
            if (l16 == 0) {
                int gp = p0 + rb * 16 + quad * 4 + i; if (gp >= end) gp = end - 1;
                psum[(size_t)brows[gp] * 16 + cg] = s;
            }
        }
}

// out = v * scale + q ; scale computed inline from psum (one block per row)
__global__ __launch_bounds__(256) void finalize_kernel(
    float* __restrict__ out, const float* __restrict__ q,
    const float* __restrict__ psum, const float* __restrict__ gval)
{
    const int row = blockIdx.x, t = threadIdx.x;
    float s = 0.f;
    #pragma unroll
    for (int j = 0; j < 16; ++j) s += psum[(size_t)row * 16 + j];
    float g = gval[row];
    float sc = g / fmaxf(g * sqrtf(s), 1e-6f);
    size_t i = (size_t)row * 256 + t;
    float4 v = ((const float4*)out)[i];
    float4 qq = ((const float4*)q)[i];
    float4 o;
    o.x = v.x * sc + qq.x;
    o.y = v.y * sc + qq.y;
    o.z = v.z * sc + qq.z;
    o.w = v.w * sc + qq.w;
    ((float4*)out)[i] = o;
}

extern "C" void kernel_launch(void* const* d_in, const int* in_sizes, int n_in,
                              void* d_out, int out_size, void* d_ws, size_t ws_size,
                              hipStream_t stream) {
    const float* q      = (const float*)d_in[0];
    const float* cls1_w = (const float*)d_in[1];
    const float* cls1_b = (const float*)d_in[2];
    const float* cls3_w = (const float*)d_in[3];
    const float* cls3_b = (const float*)d_in[4];
    const float* exp_w1 = (const float*)d_in[5];
    const float* exp_b1 = (const float*)d_in[6];
    const float* exp_w2 = (const float*)d_in[7];
    const float* exp_b2 = (const float*)d_in[8];
    float* out = (float*)d_out;

    // ---- workspace layout (~60.5 MB) ----
    char* w = (char*)d_ws;
    float* psum   = (float*)w;              w += (size_t)NB * 16 * 4;
    float* gvalp  = (float*)w;              w += (size_t)NB * 4;
    int* top1     = (int*)w;                w += (size_t)NB * 4;
    int* brows    = (int*)w;                w += (size_t)NB * 4;
    int* ambig_rows = (int*)w;              w += (size_t)NB * 4;
    int* counts   = (int*)w;                w += 16 * 4;
    int* offsets  = (int*)w;                w += 16 * 4;
    int* bpos     = (int*)w;                w += 16 * 4;
    int* ambig_cnt = (int*)w;               w += 4 * 4;
    int* tm_e     = (int*)w;                w += NT64 * 4;
    int* tm_p     = (int*)w;                w += NT64 * 4;
    int* tm_end   = (int*)w;                w += NT64 * 4;
    w = (char*)(((size_t)w + 15) & ~(size_t)15);
    unsigned short* qb   = (unsigned short*)w;  w += (size_t)NB * H * 2;     // 16.78 MB
    unsigned short* x1b  = (unsigned short*)w;  w += (size_t)NB * HH * 2;    // 8.39 MB (x1, then h)
    unsigned short* w1b  = (unsigned short*)w;  w += (size_t)HH * H * 2;     // 1.05 MB
    unsigned short* w3b  = (unsigned short*)w;  w += (size_t)NEXP * HH * 2;  // 16 KB
    unsigned short* ew1b = (unsigned short*)w;  w += (size_t)NEXP * HH * H * 2;  // 16.78 MB
    unsigned short* ew2b = (unsigned short*)w;  w += (size_t)NEXP * H * HH * 2;  // 16.78 MB
    unsigned short* hbuf = x1b;   // ALIASED: x1 consumed by logits/fixup before exp1 writes h

    cvt_kernel<<<25096, 256, 0, stream>>>(q, cls1_w, cls3_w, exp_w1, exp_w2,
                                          qb, w1b, w3b, ew1b, ew2b, counts, ambig_cnt);
    g1_kernel<<<dim3(NB / 64, 8), 64, 0, stream>>>(qb, w1b, cls1_b, x1b);
    logits_kernel<<<NB / 32, 256, 0, stream>>>(x1b, w3b, cls3_b,
                                               top1, gvalp, counts, ambig_rows, ambig_cnt);
    fixup_kernel<<<256, 256, 0, stream>>>(q, cls1_w, cls1_b, cls3_w, cls3_b,
                                          ambig_rows, ambig_cnt, top1, gvalp, counts);
    offsets_kernel<<<1, 64, 0, stream>>>(counts, offsets, bpos, tm_e, tm_p, tm_end);
    scatter_kernel<<<NB / 256, 256, 0, stream>>>(top1, bpos, brows);
    exp1_kernel<<<dim3(NT64, 8), 64, 0, stream>>>(qb, ew1b, exp_b1,
                                                  tm_e, tm_p, tm_end, brows, hbuf);
    exp2_kernel<<<dim3(NT64, 16), 64, 0, stream>>>(hbuf, ew2b, exp_b2,
                                                   tm_e, tm_p, tm_end, brows, out, psum);
    finalize_kernel<<<NB, 256, 0, stream>>>(out, q, psum, gvalp);
}